// Round 1
// baseline (185.639 us; speedup 1.0000x reference)
//
#include <hip/hip_runtime.h>
#include <math.h>

// q[row] = dot(W[row, 0:512], att[0:512]) + b[row]; one wave per row.
__global__ void proj_kernel(const float* __restrict__ att,
                            const float* __restrict__ W,
                            const float* __restrict__ b,
                            float* __restrict__ q) {
    int warp = threadIdx.x >> 6;
    int lane = threadIdx.x & 63;
    int row  = blockIdx.x * 4 + warp;   // 64 blocks * 4 waves = 256 rows
    const float4* Wr = reinterpret_cast<const float4*>(W + (size_t)row * 512);
    const float4* A  = reinterpret_cast<const float4*>(att);
    float4 w0 = Wr[lane], w1 = Wr[64 + lane];
    float4 a0 = A[lane],  a1 = A[64 + lane];
    float p = w0.x*a0.x + w0.y*a0.y + w0.z*a0.z + w0.w*a0.w
            + w1.x*a1.x + w1.y*a1.y + w1.z*a1.z + w1.w*a1.w;
    #pragma unroll
    for (int off = 32; off >= 1; off >>= 1) p += __shfl_xor(p, off);
    if (lane == 0) q[row] = p + b[row];
}

// Single pass over input: per-row score = dot(input[r], q), online softmax,
// rescaled weighted-sum accumulator. One wave per row. Per-block partial:
// [m, l, acc[256]] = 258 floats.
__global__ void fused_kernel(const float* __restrict__ input,
                             const float* __restrict__ q,
                             float* __restrict__ partials,
                             int N) {
    int warp = threadIdx.x >> 6;
    int lane = threadIdx.x & 63;
    int wid     = blockIdx.x * 4 + warp;
    int wstride = gridDim.x * 4;

    // lane's 4 columns of q, held in registers for the whole pass
    float4 qv = reinterpret_cast<const float4*>(q)[lane];

    float  m = -INFINITY, l = 0.f;
    float4 acc = make_float4(0.f, 0.f, 0.f, 0.f);

    for (int r = wid; r < N; r += wstride) {
        float4 v = reinterpret_cast<const float4*>(input + (size_t)r * 256)[lane];
        float p = v.x*qv.x + v.y*qv.y + v.z*qv.z + v.w*qv.w;
        #pragma unroll
        for (int off = 32; off >= 1; off >>= 1) p += __shfl_xor(p, off);
        // p now holds the full score in every lane; branch is wave-uniform
        if (p > m) {
            float c = __expf(m - p);    // exp(-inf) = 0 handles first row
            l = l * c + 1.f;
            acc.x = acc.x * c + v.x;
            acc.y = acc.y * c + v.y;
            acc.z = acc.z * c + v.z;
            acc.w = acc.w * c + v.w;
            m = p;
        } else {
            float e = __expf(p - m);
            l += e;
            acc.x += e * v.x;
            acc.y += e * v.y;
            acc.z += e * v.z;
            acc.w += e * v.w;
        }
    }

    // merge the block's 4 waves via LDS
    __shared__ float sm[4];
    __shared__ float sl[4];
    __shared__ float sacc[4][256];
    float* dstp = &sacc[warp][lane * 4];
    dstp[0] = acc.x; dstp[1] = acc.y; dstp[2] = acc.z; dstp[3] = acc.w;
    if (lane == 0) { sm[warp] = m; sl[warp] = l; }
    __syncthreads();

    int t = threadIdx.x;
    float M = fmaxf(fmaxf(sm[0], sm[1]), fmaxf(sm[2], sm[3]));
    float L = 0.f, o = 0.f;
    #pragma unroll
    for (int w = 0; w < 4; ++w) {
        float c = __expf(sm[w] - M);
        L += c * sl[w];
        o += c * sacc[w][t];
    }
    float* bp = partials + (size_t)blockIdx.x * 258;
    if (t == 0) { bp[0] = M; bp[1] = L; }
    bp[2 + t] = o;
}

// Log-sum-exp merge of per-block partials; single block of 256 threads.
__global__ void finalize_kernel(const float* __restrict__ partials,
                                float* __restrict__ out,
                                int nblocks) {
    __shared__ float red[256];
    __shared__ float cw[2048];
    int t = threadIdx.x;

    float M = -INFINITY;
    for (int i = t; i < nblocks; i += 256)
        M = fmaxf(M, partials[(size_t)i * 258]);
    red[t] = M; __syncthreads();
    for (int s = 128; s >= 1; s >>= 1) {
        if (t < s) red[t] = fmaxf(red[t], red[t + s]);
        __syncthreads();
    }
    M = red[0]; __syncthreads();

    float L = 0.f;
    for (int i = t; i < nblocks; i += 256) {
        float c = __expf(partials[(size_t)i * 258] - M);
        cw[i] = c;
        L += c * partials[(size_t)i * 258 + 1];
    }
    red[t] = L; __syncthreads();
    for (int s = 128; s >= 1; s >>= 1) {
        if (t < s) red[t] += red[t + s];
        __syncthreads();
    }
    L = red[0];

    float o = 0.f;
    for (int w = 0; w < nblocks; ++w)
        o += cw[w] * partials[(size_t)w * 258 + 2 + t];
    out[t] = o / L;
}

extern "C" void kernel_launch(void* const* d_in, const int* in_sizes, int n_in,
                              void* d_out, int out_size, void* d_ws, size_t ws_size,
                              hipStream_t stream) {
    const float* att   = (const float*)d_in[0];   // [1, 512]
    const float* input = (const float*)d_in[1];   // [N, 256]
    const float* W     = (const float*)d_in[2];   // [256, 512]
    const float* b     = (const float*)d_in[3];   // [256]
    float* out = (float*)d_out;                   // [256]
    int N = in_sizes[1] / 256;

    // workspace layout: q[256] | partials[nblocks * 258]
    int nblocks = 2048;
    while ((256 + (size_t)nblocks * 258) * sizeof(float) > ws_size && nblocks > 64)
        nblocks >>= 1;
    float* q        = (float*)d_ws;
    float* partials = q + 256;

    proj_kernel<<<64, 256, 0, stream>>>(att, W, b, q);
    fused_kernel<<<nblocks, 256, 0, stream>>>(input, q, partials, N);
    finalize_kernel<<<1, 256, 0, stream>>>(partials, out, nblocks);
}

// Round 2
// 62.678 us; speedup vs baseline: 2.9618x; 2.9618x over previous
//
#include <hip/hip_runtime.h>
#include <math.h>

// q[row] = dot(W[row, 0:512], att[0:512]) + b[row]; one wave per row.
__global__ void proj_kernel(const float* __restrict__ att,
                            const float* __restrict__ W,
                            const float* __restrict__ b,
                            float* __restrict__ q) {
    int warp = threadIdx.x >> 6;
    int lane = threadIdx.x & 63;
    int row  = blockIdx.x * 4 + warp;   // 64 blocks * 4 waves = 256 rows
    const float4* Wr = reinterpret_cast<const float4*>(W + (size_t)row * 512);
    const float4* A  = reinterpret_cast<const float4*>(att);
    float4 w0 = Wr[lane], w1 = Wr[64 + lane];
    float4 a0 = A[lane],  a1 = A[64 + lane];
    float p = w0.x*a0.x + w0.y*a0.y + w0.z*a0.z + w0.w*a0.w
            + w1.x*a1.x + w1.y*a1.y + w1.z*a1.z + w1.w*a1.w;
    #pragma unroll
    for (int off = 32; off >= 1; off >>= 1) p += __shfl_xor(p, off);
    if (lane == 0) q[row] = p + b[row];
}

// Single pass over input: per-row score = dot(input[r], q), online softmax,
// rescaled weighted-sum accumulator. One wave per row, grid-stride.
// Partials in SoA layout: pm[nb], pl[nb], pacc[nb][256] (all coalesced).
__global__ void fused_kernel(const float* __restrict__ input,
                             const float* __restrict__ q,
                             float* __restrict__ pm,
                             float* __restrict__ pl,
                             float* __restrict__ pacc,
                             int N) {
    int warp = threadIdx.x >> 6;
    int lane = threadIdx.x & 63;
    int wid     = blockIdx.x * 4 + warp;
    int wstride = gridDim.x * 4;

    float4 qv = reinterpret_cast<const float4*>(q)[lane];

    float  m = -INFINITY, l = 0.f;
    float4 acc = make_float4(0.f, 0.f, 0.f, 0.f);

    for (int r = wid; r < N; r += wstride) {
        float4 v = reinterpret_cast<const float4*>(input + (size_t)r * 256)[lane];
        float p = v.x*qv.x + v.y*qv.y + v.z*qv.z + v.w*qv.w;
        #pragma unroll
        for (int off = 32; off >= 1; off >>= 1) p += __shfl_xor(p, off);
        // p holds the full score in every lane; branch is wave-uniform
        if (p > m) {
            float c = __expf(m - p);    // exp(-inf) = 0 handles first row
            l = l * c + 1.f;
            acc.x = acc.x * c + v.x;
            acc.y = acc.y * c + v.y;
            acc.z = acc.z * c + v.z;
            acc.w = acc.w * c + v.w;
            m = p;
        } else {
            float e = __expf(p - m);
            l += e;
            acc.x += e * v.x;
            acc.y += e * v.y;
            acc.z += e * v.z;
            acc.w += e * v.w;
        }
    }

    // merge the block's 4 waves via LDS
    __shared__ float sm[4];
    __shared__ float sl[4];
    __shared__ float sacc[4][256];
    float* dstp = &sacc[warp][lane * 4];
    dstp[0] = acc.x; dstp[1] = acc.y; dstp[2] = acc.z; dstp[3] = acc.w;
    if (lane == 0) { sm[warp] = m; sl[warp] = l; }
    __syncthreads();

    int t = threadIdx.x;
    float M = fmaxf(fmaxf(sm[0], sm[1]), fmaxf(sm[2], sm[3]));
    float L = 0.f, o = 0.f;
    #pragma unroll
    for (int w = 0; w < 4; ++w) {
        float c = __expf(sm[w] - M);
        L += c * sl[w];
        o += c * sacc[w][t];
    }
    if (t == 0) { pm[blockIdx.x] = M; pl[blockIdx.x] = L; }
    pacc[(size_t)blockIdx.x * 256 + t] = o;
}

// Stage 2: each block LSE-merges GROUP consecutive partials. Coalesced acc
// reads (256 consecutive floats per iteration); m/l reads are wave-uniform.
template<int GROUP>
__global__ void merge_kernel(const float* __restrict__ pm,
                             const float* __restrict__ pl,
                             const float* __restrict__ pacc,
                             float* __restrict__ m2,
                             float* __restrict__ l2,
                             float* __restrict__ acc2) {
    int b = blockIdx.x;
    int t = threadIdx.x;
    int base = b * GROUP;

    float M = -INFINITY;
    #pragma unroll
    for (int w = 0; w < GROUP; ++w) M = fmaxf(M, pm[base + w]);

    float L = 0.f, o = 0.f;
    #pragma unroll
    for (int w = 0; w < GROUP; ++w) {
        float c = __expf(pm[base + w] - M);
        L += c * pl[base + w];
        o += c * pacc[(size_t)(base + w) * 256 + t];
    }
    if (t == 0) { m2[b] = M; l2[b] = L; }
    acc2[(size_t)b * 256 + t] = o;
}

// Stage 3: final merge over nb2 partials; 1 block of 256 threads.
__global__ void finalize_kernel(const float* __restrict__ m2,
                                const float* __restrict__ l2,
                                const float* __restrict__ acc2,
                                float* __restrict__ out,
                                int nb2) {
    int t = threadIdx.x;
    float M = -INFINITY;
    for (int w = 0; w < nb2; ++w) M = fmaxf(M, m2[w]);
    float L = 0.f, o = 0.f;
    for (int w = 0; w < nb2; ++w) {
        float c = __expf(m2[w] - M);
        L += c * l2[w];
        o += c * acc2[(size_t)w * 256 + t];
    }
    out[t] = o / L;
}

extern "C" void kernel_launch(void* const* d_in, const int* in_sizes, int n_in,
                              void* d_out, int out_size, void* d_ws, size_t ws_size,
                              hipStream_t stream) {
    const float* att   = (const float*)d_in[0];   // [1, 512]
    const float* input = (const float*)d_in[1];   // [N, 256]
    const float* W     = (const float*)d_in[2];   // [256, 512]
    const float* b     = (const float*)d_in[3];   // [256]
    float* out = (float*)d_out;                   // [256]
    int N = in_sizes[1] / 256;

    const int GROUP = 32;
    int nb = 2048;
    // ws layout: q[256] | pm[nb] | pl[nb] | pacc[nb*256] | m2[nb2] | l2[nb2] | acc2[nb2*256]
    while (nb > 64) {
        int n2 = nb / GROUP;
        size_t need = (256 + 2 * (size_t)nb + (size_t)nb * 256
                       + 2 * (size_t)n2 + (size_t)n2 * 256) * sizeof(float);
        if (need <= ws_size) break;
        nb >>= 1;
    }
    int nb2 = nb / GROUP;

    float* q    = (float*)d_ws;
    float* pm   = q + 256;
    float* pl   = pm + nb;
    float* pacc = pl + nb;
    float* m2   = pacc + (size_t)nb * 256;
    float* l2   = m2 + nb2;
    float* acc2 = l2 + nb2;

    proj_kernel<<<64, 256, 0, stream>>>(att, W, b, q);
    fused_kernel<<<nb, 256, 0, stream>>>(input, q, pm, pl, pacc, N);
    merge_kernel<GROUP><<<nb2, 256, 0, stream>>>(pm, pl, pacc, m2, l2, acc2);
    finalize_kernel<<<1, 256, 0, stream>>>(m2, l2, acc2, out, nb2);
}